// Round 17
// baseline (109.415 us; speedup 1.0000x reference)
//
#include <hip/hip_runtime.h>
#include <math.h>

#define VOCAB 50000
#define EMBED 128
#define SEQ   200
#define HID   30
#define BATCH 4096

// MODEL (r16 fit): rnn = LDS throughput (8 waves x 6 ops ~ 576 cyc/CU-step)
// + exposed serial latency (read ~120 + swz ~120 + tanh ~40) ~= 890 measured.
// r17: ONE ds_read_b128/lane/step (chunk j16&3 of own k-half) + 3-step DPP
// quad_perm butterfly (xor1/xor2, VALU pipe) assembles the 16 h values.
// Weight order derived by the r11-proven runtime probe (same DPP ops applied
// to the k index). Exchange stays r16's proven ds_swizzle(xor16).
// LDS/wave-step: 3 ops. embproj byte-frozen from r16.
typedef float4 __attribute__((__may_alias__)) f4ma;

__device__ __forceinline__ float tanh_fast(float x) {
    float e = __expf(2.0f * x);
    return 1.0f - __fdividef(2.0f, e + 1.0f);
}
__device__ __forceinline__ float swz16_f(float x) {   // lane ^= 16 (r11/r16-proven)
    return __int_as_float(__builtin_amdgcn_ds_swizzle(__float_as_int(x), 0x401F));
}
// quad_perm DPP: xor1 = [1,0,3,2] = 0xB1, xor2 = [2,3,0,1] = 0x4E
__device__ __forceinline__ int qpx1_i(int x) {
    return __builtin_amdgcn_update_dpp(0, x, 0xB1, 0xF, 0xF, false);
}
__device__ __forceinline__ int qpx2_i(int x) {
    return __builtin_amdgcn_update_dpp(0, x, 0x4E, 0xF, 0xF, false);
}
__device__ __forceinline__ float qpx1_f(float x) {
    return __int_as_float(qpx1_i(__float_as_int(x)));
}
__device__ __forceinline__ float qpx2_f(float x) {
    return __int_as_float(qpx2_i(__float_as_int(x)));
}

// Kernel 1: embP[v][j] = sum_e emb[v][e]*Wx[e][j] + b_rnn[j]
// BYTE-IDENTICAL to r16 (passed, ~15-20us). Do not touch this round.
__global__ __launch_bounds__(256, 2) void embproj_kernel(
    const float* __restrict__ emb, const float* __restrict__ Wx,
    const float* __restrict__ brnn, float* __restrict__ embP)
{
    int tid  = threadIdx.x;
    int wv   = tid >> 6;
    int l    = tid & 63;
    int j16  = l & 15;
    int p    = (l >> 4) & 1;
    int g    = l >> 5;
    int col  = j16 + 16 * g;
    int colc = (col < HID) ? col : (HID - 1);
    int k0   = 64 * p;

    float whx[64];
    #pragma unroll
    for (int i = 0; i < 64; ++i)
        whx[i] = Wx[(k0 + i) * HID + colc];
    float bj = brnn[colc];

    int base = (blockIdx.x * 4 + wv) * 25;

    float4 eA[16], eB[16];
    #define LOADROW(dst, v) { \
        int vc = min((v), VOCAB - 1); \
        const f4ma* e4 = (const f4ma*)(emb + (size_t)vc * EMBED + k0); \
        _Pragma("unroll") \
        for (int q = 0; q < 16; ++q) dst[q] = e4[q]; \
    }
    #define COMPUTE(src, v) { \
        float a0 = 0.f, a1 = 0.f, a2 = 0.f, a3 = 0.f; \
        _Pragma("unroll") \
        for (int q = 0; q < 16; ++q) { \
            a0 += src[q].x * whx[4*q+0]; \
            a1 += src[q].y * whx[4*q+1]; \
            a2 += src[q].z * whx[4*q+2]; \
            a3 += src[q].w * whx[4*q+3]; \
        } \
        float own  = (a0 + a1) + (a2 + a3); \
        float full = bj + (own + swz16_f(own)); \
        if (p == 0 && col < HID && (v) < VOCAB) \
            embP[(size_t)(v) * HID + col] = full; \
    }

    LOADROW(eA, base + 0);
    for (int r = 0; r < 25; r += 2) {
        LOADROW(eB, base + r + 1);
        COMPUTE(eA, base + r);
        LOADROW(eA, base + r + 2);
        COMPUTE(eB, base + r + 1);
    }
    #undef LOADROW
    #undef COMPUTE
}

// Kernel 2: fused RNN recurrence + dense head.
// Wave = 2 rows x 32 lanes; lane (j16 = l&15, p = (l>>4)&1, row = l>>5)
// owns col j = j16+16p of its row. Per step:
//   1 ds_read_b128  : chunk (j16&3) of h[row][16p..16p+16)
//   12 v_mov_dpp    : quad butterfly -> all 16 h values in regs (VALU pipe)
//   32 FMA          : partials pA (col j16), pB (col j16+16) over k-half p
//   1 ds_swizzle    : exchange send=p?pA:pB with partner l^16 (r16-proven)
//   tanh + 1 ds_write (gated j<HID) + sched_barrier
// Weights whA/whB ordered by the DPP arrival probe (robust to direction).
__global__ __launch_bounds__(256, 2) void rnn_head_kernel(
    const int* __restrict__ tokens, const float* __restrict__ embP,
    const float* __restrict__ Wh,
    const float* __restrict__ W1, const float* __restrict__ b1,
    const float* __restrict__ W2, const float* __restrict__ b2,
    const float* __restrict__ W3, const float* __restrict__ b3,
    const float* __restrict__ Wo, const float* __restrict__ bo,
    float* __restrict__ out)
{
    __shared__ __align__(16) float hL[8][32];
    __shared__ float d1L[8][128];
    __shared__ float d2L[8][64];

    int tid  = threadIdx.x;
    int wv   = tid >> 6;           // wave 0..3
    int l    = tid & 63;
    int row  = l >> 5;             // row within wave
    int j    = l & 31;             // own column = j16 + 16p (see below)
    int j16  = l & 15;
    int p    = (l >> 4) & 1;       // k-half
    int rloc = wv * 2 + row;       // row within block
    int b    = blockIdx.x * 8 + rloc;

    const int* trow = tokens + (size_t)b * SEQ;
    int jc = (j < HID) ? j : (HID - 1);

    hL[rloc][j] = 0.0f;            // h0 = 0; cols 30,31 stay 0 forever
    __builtin_amdgcn_sched_barrier(0);

    // ---- arrival-order probe: run the EXACT butterfly ops on the k base
    // index; slot s (s=0..3) holds chunk with base ks[s] after the same ops.
    int kbase = 16 * p + 4 * (j16 & 3);
    int ks0 = kbase;
    int ks1 = qpx1_i(ks0);
    int ks2 = qpx2_i(ks0);
    int ks3 = qpx2_i(ks1);

    int cB = j16 + 16;
    float whA[16], whB[16];
    {
        int ks[4] = { ks0, ks1, ks2, ks3 };
        #pragma unroll
        for (int s = 0; s < 4; ++s) {
            #pragma unroll
            for (int e = 0; e < 4; ++e) {
                int k = ks[s] + e;                     // 0..31
                whA[4*s+e] = (k < HID) ? Wh[k * HID + j16] : 0.0f;
                whB[4*s+e] = (k < HID && cB < HID) ? Wh[k * HID + cB] : 0.0f;
            }
        }
    }

    // two-level pipeline: xq[s] = xp for step t+s; tr[s] = token for t+8+s
    float xq[8]; int tr[8];
    #pragma unroll
    for (int s = 0; s < 8; ++s) {
        xq[s] = embP[(size_t)trow[s] * HID + jc];
        tr[s] = trow[8 + s];
    }

    const f4ma* chunkp = (const f4ma*)(&hL[rloc][kbase]);

    for (int t = 0; t < SEQ; t += 8) {
        #pragma unroll
        for (int s = 0; s < 8; ++s) {
            // ONE ds_read_b128: own chunk (16 distinct chunks across the
            // wave cover both rows exactly once -> 2-way banks, free)
            f4ma ch = *chunkp;

            // ring refills in the read-latency window
            float xp = xq[s];
            xq[s] = embP[(size_t)tr[s] * HID + jc];
            int tn = t + 16 + s; tn = (tn < SEQ) ? tn : SEQ - 1;
            tr[s] = trow[tn];

            // quad butterfly: slots 0..3 = chunks kbase, ^1, ^2, ^3
            float hv[16];
            hv[0] = ch.x; hv[1] = ch.y; hv[2] = ch.z; hv[3] = ch.w;
            hv[4]  = qpx1_f(ch.x); hv[5]  = qpx1_f(ch.y);
            hv[6]  = qpx1_f(ch.z); hv[7]  = qpx1_f(ch.w);
            hv[8]  = qpx2_f(ch.x); hv[9]  = qpx2_f(ch.y);
            hv[10] = qpx2_f(ch.z); hv[11] = qpx2_f(ch.w);
            hv[12] = qpx2_f(hv[4]); hv[13] = qpx2_f(hv[5]);
            hv[14] = qpx2_f(hv[6]); hv[15] = qpx2_f(hv[7]);

            // both columns' partials over own k-half (4 chains, depth 8)
            float a0=0.f, a1=0.f, b0=0.f, b1=0.f;
            #pragma unroll
            for (int kk = 0; kk < 16; kk += 2) {
                a0 += hv[kk]   * whA[kk];
                a1 += hv[kk+1] * whA[kk+1];
                b0 += hv[kk]   * whB[kk];
                b1 += hv[kk+1] * whB[kk+1];
            }
            float pA = a0 + a1;           // col j16    , k-half p
            float pB = b0 + b1;           // col j16+16 , k-half p
            float own  = p ? pB : pA;
            float send = p ? pA : pB;     // partner (l^16) needs this
            float recv = swz16_f(send);
            float hn = tanh_fast(xp + (own + recv));
            if (j < HID) hL[rloc][j] = hn;
            __builtin_amdgcn_sched_barrier(0);   // store precedes next read
        }
    }

    // ---- dense head: r7/r16 code verbatim, each 32-lane half = one row ----
    {
        #pragma unroll
        for (int qq = 0; qq < 4; ++qq) {
            int c = j + 32 * qq;
            float acc = b1[c];
            #pragma unroll
            for (int k = 0; k < HID; ++k) acc += hL[rloc][k] * W1[k * 128 + c];
            d1L[rloc][c] = fmaxf(acc, 0.0f);
        }
        #pragma unroll
        for (int qq = 0; qq < 2; ++qq) {
            int c = j + 32 * qq;
            float acc = b2[c];
            #pragma unroll 8
            for (int k = 0; k < 128; ++k) acc += d1L[rloc][k] * W2[k * 64 + c];
            d2L[rloc][c] = fmaxf(acc, 0.0f);
        }
        float acc3 = b3[j];
        #pragma unroll 8
        for (int k = 0; k < 64; ++k) acc3 += d2L[rloc][k] * W3[k * 32 + j];
        acc3 = fmaxf(acc3, 0.0f);
        float prod = acc3 * Wo[j];
        #pragma unroll
        for (int m = 16; m > 0; m >>= 1) prod += __shfl_xor(prod, m, 32);
        if (j == 0) out[b] = 1.0f / (1.0f + __expf(-(prod + bo[0])));
    }
}

extern "C" void kernel_launch(void* const* d_in, const int* in_sizes, int n_in,
                              void* d_out, int out_size, void* d_ws, size_t ws_size,
                              hipStream_t stream) {
    (void)in_sizes; (void)n_in; (void)out_size; (void)ws_size;
    const int*   tokens = (const int*)  d_in[0];
    const float* emb    = (const float*)d_in[1];
    const float* Wx     = (const float*)d_in[2];
    const float* Wh     = (const float*)d_in[3];
    const float* brnn   = (const float*)d_in[4];
    const float* W1     = (const float*)d_in[5];
    const float* b1     = (const float*)d_in[6];
    const float* W2     = (const float*)d_in[7];
    const float* b2     = (const float*)d_in[8];
    const float* W3     = (const float*)d_in[9];
    const float* b3     = (const float*)d_in[10];
    const float* Wo     = (const float*)d_in[11];
    const float* bo     = (const float*)d_in[12];
    float* out  = (float*)d_out;
    float* embP = (float*)d_ws;   // 50000*30*4 = 6 MB

    embproj_kernel<<<512, 256, 0, stream>>>(emb, Wx, brnn, embP);
    rnn_head_kernel<<<BATCH / 8, 256, 0, stream>>>(
        tokens, embP, Wh, W1, b1, W2, b2, W3, b3, Wo, bo, out);
}

// Round 18
// 95.773 us; speedup vs baseline: 1.1424x; 1.1424x over previous
//
#include <hip/hip_runtime.h>
#include <math.h>

#define VOCAB 50000
#define EMBED 128
#define SEQ   200
#define HID   30
#define BATCH 4096

// MODEL (r16/r17 fit): rnn = LDS throughput (~430 cyc/CU-step) + serial
// chain with TWO LDS round-trips (h read ~120 + xor16 ds_swizzle ~120).
// r17's DPP butterfly added dependent-position VALU latency -> refuted.
// r18: keep r16's compute EXACTLY; swap the xor16 ds_swizzle for
// v_permlane32_swap (VALU pipe, partner = l^32) by remapping lane bits:
// row = bit4, k-half p = bit5. Selection slot chosen by a RUNTIME PROBE
// (apply the instruction to the lane index; pick the slot that equals l^32)
// -- correct regardless of direction convention. Arithmetic bit-identical
// to r16 -> absmax 0.0 expected. embproj + head byte-frozen.
typedef float4 __attribute__((__may_alias__)) f4ma;
typedef unsigned int uint2v __attribute__((ext_vector_type(2)));

__device__ __forceinline__ float tanh_fast(float x) {
    float e = __expf(2.0f * x);
    return 1.0f - __fdividef(2.0f, e + 1.0f);
}
__device__ __forceinline__ float swz16_f(float x) {   // used by embproj only
    return __int_as_float(__builtin_amdgcn_ds_swizzle(__float_as_int(x), 0x401F));
}

// Kernel 1: embP[v][j] = sum_e emb[v][e]*Wx[e][j] + b_rnn[j]
// BYTE-IDENTICAL to r16/r17 (passed twice). Do not touch.
__global__ __launch_bounds__(256, 2) void embproj_kernel(
    const float* __restrict__ emb, const float* __restrict__ Wx,
    const float* __restrict__ brnn, float* __restrict__ embP)
{
    int tid  = threadIdx.x;
    int wv   = tid >> 6;
    int l    = tid & 63;
    int j16  = l & 15;
    int p    = (l >> 4) & 1;
    int g    = l >> 5;
    int col  = j16 + 16 * g;
    int colc = (col < HID) ? col : (HID - 1);
    int k0   = 64 * p;

    float whx[64];
    #pragma unroll
    for (int i = 0; i < 64; ++i)
        whx[i] = Wx[(k0 + i) * HID + colc];
    float bj = brnn[colc];

    int base = (blockIdx.x * 4 + wv) * 25;

    float4 eA[16], eB[16];
    #define LOADROW(dst, v) { \
        int vc = min((v), VOCAB - 1); \
        const f4ma* e4 = (const f4ma*)(emb + (size_t)vc * EMBED + k0); \
        _Pragma("unroll") \
        for (int q = 0; q < 16; ++q) dst[q] = e4[q]; \
    }
    #define COMPUTE(src, v) { \
        float a0 = 0.f, a1 = 0.f, a2 = 0.f, a3 = 0.f; \
        _Pragma("unroll") \
        for (int q = 0; q < 16; ++q) { \
            a0 += src[q].x * whx[4*q+0]; \
            a1 += src[q].y * whx[4*q+1]; \
            a2 += src[q].z * whx[4*q+2]; \
            a3 += src[q].w * whx[4*q+3]; \
        } \
        float own  = (a0 + a1) + (a2 + a3); \
        float full = bj + (own + swz16_f(own)); \
        if (p == 0 && col < HID && (v) < VOCAB) \
            embP[(size_t)(v) * HID + col] = full; \
    }

    LOADROW(eA, base + 0);
    for (int r = 0; r < 25; r += 2) {
        LOADROW(eB, base + r + 1);
        COMPUTE(eA, base + r);
        LOADROW(eA, base + r + 2);
        COMPUTE(eB, base + r + 1);
    }
    #undef LOADROW
    #undef COMPUTE
}

// Kernel 2: fused RNN recurrence + dense head.
// Wave = 2 rows x 32 cols; lane bits: j16 = l&15, row = (l>>4)&1, p = l>>5.
// Own col j = j16+16p. Per step: 4x ds_read_b128 (own k-half of own row,
// <=2-way banks) -> 32 FMA (both cols' partials over half p) ->
// v_permlane32_swap (VALU; partner l^32 = same row, other half) -> tanh ->
// gated store. LDS/wave-step: 5 ops, and the serial chain has ONE LDS RT.
// Arithmetic identical to r16: hn = tanh(xp + (own + recv)).
__global__ __launch_bounds__(128) void rnn_head_kernel(
    const int* __restrict__ tokens, const float* __restrict__ embP,
    const float* __restrict__ Wh,
    const float* __restrict__ W1, const float* __restrict__ b1,
    const float* __restrict__ W2, const float* __restrict__ b2,
    const float* __restrict__ W3, const float* __restrict__ b3,
    const float* __restrict__ Wo, const float* __restrict__ bo,
    float* __restrict__ out)
{
    __shared__ __align__(16) float hL[4][32];
    __shared__ float d1L[4][128];
    __shared__ float d2L[4][64];

    int tid  = threadIdx.x;
    int wv   = tid >> 6;            // wave 0..1
    int l    = tid & 63;
    int j16  = l & 15;
    int row  = (l >> 4) & 1;        // row within wave (bit 4)
    int p    = l >> 5;              // k-half (bit 5) -> partner = l^32
    int j    = j16 + 16 * p;        // own column
    int rloc = wv * 2 + row;        // row within block, 0..3
    int b    = blockIdx.x * 4 + rloc;

    const int* trow = tokens + (size_t)b * SEQ;
    int jc = (j < HID) ? j : (HID - 1);

    hL[rloc][j] = 0.0f;             // h0 = 0 (64 lanes cover 2 rows x 32 cols)
    __builtin_amdgcn_sched_barrier(0);

    // runtime probe: which swap-result slot holds the partner (l^32) value
    bool useR0;
    {
        unsigned li = (unsigned)l;
        uint2v rp = __builtin_amdgcn_permlane32_swap(li, li, false, false);
        useR0 = (rp[0] == (unsigned)(l ^ 32));
    }

    int cB = j16 + 16;
    float whA[16], whB[16];
    #pragma unroll
    for (int kk = 0; kk < 16; ++kk) {
        int k = 16 * p + kk;
        whA[kk] = (k < HID) ? Wh[k * HID + j16] : 0.0f;
        whB[kk] = (k < HID && cB < HID) ? Wh[k * HID + cB] : 0.0f;
    }

    // two-level pipeline: xq[s] = xp for step t+s; tr[s] = token for t+8+s
    float xq[8]; int tr[8];
    #pragma unroll
    for (int s = 0; s < 8; ++s) {
        xq[s] = embP[(size_t)trow[s] * HID + jc];
        tr[s] = trow[8 + s];
    }

    for (int t = 0; t < SEQ; t += 8) {
        #pragma unroll
        for (int s = 0; s < 8; ++s) {
            // 4x ds_read_b128: own k-half of own row (2-way banks, free)
            float hv[16];
            const f4ma* h4 = (const f4ma*)(&hL[rloc][16 * p]);
            #pragma unroll
            for (int qq = 0; qq < 4; ++qq) {
                f4ma hh = h4[qq];
                hv[4*qq+0] = hh.x; hv[4*qq+1] = hh.y;
                hv[4*qq+2] = hh.z; hv[4*qq+3] = hh.w;
            }
            // ring refills in the read-latency window
            float xp = xq[s];
            xq[s] = embP[(size_t)tr[s] * HID + jc];
            int tn = t + 16 + s; tn = (tn < SEQ) ? tn : SEQ - 1;
            tr[s] = trow[tn];

            // both columns' partials over own k-half (4 chains, depth 8)
            float a0=0.f, a1=0.f, b0=0.f, b1=0.f;
            #pragma unroll
            for (int kk = 0; kk < 16; kk += 2) {
                a0 += hv[kk]   * whA[kk];
                a1 += hv[kk+1] * whA[kk+1];
                b0 += hv[kk]   * whB[kk];
                b1 += hv[kk+1] * whB[kk+1];
            }
            float pA = a0 + a1;            // col j16    , k-half p
            float pB = b0 + b1;            // col j16+16 , k-half p
            float own  = p ? pB : pA;      // own col's partial
            float send = p ? pA : pB;      // partner (l^32) needs this
            unsigned si = __float_as_uint(send);
            uint2v sw = __builtin_amdgcn_permlane32_swap(si, si, false, false);
            float recv = __uint_as_float(useR0 ? sw[0] : sw[1]);
            float hn = tanh_fast(xp + (own + recv));
            if (j < HID) hL[rloc][j] = hn;
            __builtin_amdgcn_sched_barrier(0);   // store precedes next read
        }
    }

    // ---- dense head: r16 code verbatim (its own lane mapping) ----
    {
        int half = l >> 5, j32 = l & 31;
        int rh = wv * 2 + half;
        int bB = blockIdx.x * 4 + rh;
        #pragma unroll
        for (int qq = 0; qq < 4; ++qq) {
            int c = j32 + 32 * qq;
            float acc = b1[c];
            #pragma unroll
            for (int k = 0; k < HID; ++k) acc += hL[rh][k] * W1[k * 128 + c];
            d1L[rh][c] = fmaxf(acc, 0.0f);
        }
        #pragma unroll
        for (int qq = 0; qq < 2; ++qq) {
            int c = j32 + 32 * qq;
            float acc = b2[c];
            #pragma unroll 8
            for (int k = 0; k < 128; ++k) acc += d1L[rh][k] * W2[k * 64 + c];
            d2L[rh][c] = fmaxf(acc, 0.0f);
        }
        float acc3 = b3[j32];
        #pragma unroll 8
        for (int k = 0; k < 64; ++k) acc3 += d2L[rh][k] * W3[k * 32 + j32];
        acc3 = fmaxf(acc3, 0.0f);
        float prod = acc3 * Wo[j32];
        #pragma unroll
        for (int m = 16; m > 0; m >>= 1) prod += __shfl_xor(prod, m, 32);
        if (j32 == 0) out[bB] = 1.0f / (1.0f + __expf(-(prod + bo[0])));
    }
}

extern "C" void kernel_launch(void* const* d_in, const int* in_sizes, int n_in,
                              void* d_out, int out_size, void* d_ws, size_t ws_size,
                              hipStream_t stream) {
    (void)in_sizes; (void)n_in; (void)out_size; (void)ws_size;
    const int*   tokens = (const int*)  d_in[0];
    const float* emb    = (const float*)d_in[1];
    const float* Wx     = (const float*)d_in[2];
    const float* Wh     = (const float*)d_in[3];
    const float* brnn   = (const float*)d_in[4];
    const float* W1     = (const float*)d_in[5];
    const float* b1     = (const float*)d_in[6];
    const float* W2     = (const float*)d_in[7];
    const float* b2     = (const float*)d_in[8];
    const float* W3     = (const float*)d_in[9];
    const float* b3     = (const float*)d_in[10];
    const float* Wo     = (const float*)d_in[11];
    const float* bo     = (const float*)d_in[12];
    float* out  = (float*)d_out;
    float* embP = (float*)d_ws;   // 50000*30*4 = 6 MB

    embproj_kernel<<<512, 256, 0, stream>>>(emb, Wx, brnn, embP);
    rnn_head_kernel<<<BATCH / 4, 128, 0, stream>>>(
        tokens, embP, Wh, W1, b1, W2, b2, W3, b3, Wo, bo, out);
}